// Round 9
// baseline (867.919 us; speedup 1.0000x reference)
//
#include <hip/hip_runtime.h>
#include <hip/hip_bf16.h>
#include <stdint.h>

typedef short bf16x8 __attribute__((ext_vector_type(8)));
typedef float f32x4 __attribute__((ext_vector_type(4)));
typedef unsigned short u16x4 __attribute__((ext_vector_type(4)));
typedef unsigned int u32x2 __attribute__((ext_vector_type(2)));

#define MFMA16(a, b, c) __builtin_amdgcn_mfma_f32_16x16x32_bf16((a), (b), (c), 0, 0, 0)

static __device__ __forceinline__ void gload_lds16(const void* g, void* l) {
  typedef const __attribute__((address_space(1))) void* gp_t;
  typedef __attribute__((address_space(3))) void* lp_t;
  __builtin_amdgcn_global_load_lds((gp_t)g, (lp_t)l, 16, 0, 0);
}

// HW packed f32->bf16 (RNE), 1 VALU op for 2 values
static __device__ __forceinline__ unsigned cvt_pk_bf16(float a, float b) {
  unsigned r;
  asm("v_cvt_pk_bf16_f32 %0, %1, %2" : "=v"(r) : "v"(a), "v"(b));
  return r;
}

// ---------------- conversion kernels ----------------
__global__ void cvt_x_k(const float* __restrict__ in, __hip_bfloat162* __restrict__ out, int n2) {
  int i = blockIdx.x * blockDim.x + threadIdx.x;
  int stride = gridDim.x * blockDim.x;
  const float2* in2 = (const float2*)in;
  for (; i < n2; i += stride) {
    float2 v = in2[i];
    out[i] = __float22bfloat162_rn(v);
  }
}

__global__ void cvt_w_k(const float* __restrict__ w0, const float* __restrict__ w1,
                        const float* __restrict__ w2, const float* __restrict__ w3,
                        __hip_bfloat162* __restrict__ out, int n2) {
  const float* w = (blockIdx.z == 0) ? w0 : (blockIdx.z == 1) ? w1 : (blockIdx.z == 2) ? w2 : w3;
  __hip_bfloat162* o = out + (size_t)blockIdx.z * n2;
  int i = blockIdx.x * blockDim.x + threadIdx.x;
  int stride = gridDim.x * blockDim.x;
  const float2* in2 = (const float2*)w;
  for (; i < n2; i += stride) {
    float2 v = in2[i];
    o[i] = __float22bfloat162_rn(v);
  }
}

// ---------------- fused QKV projection GEMM ----------------
// BM=256 x BN=128, 8 waves (4M x 2N, 64x64 each), BK=32, 2-phase dbuf.
// C[m][n] = sum_k xb[m][k] * W[n][k] + bias[n]
// z=0 -> q (scaled by 0.125*log2e, layout [bh][l][hd]); z=1 -> k; z=2 -> v^T ([bh][hd][L])
__global__ __launch_bounds__(512, 6) void proj_gemm_k(
    const __hip_bfloat16* __restrict__ xb, const __hip_bfloat16* __restrict__ wb,
    const float* __restrict__ bq, const float* __restrict__ bk, const float* __restrict__ bv,
    __hip_bfloat16* __restrict__ qout, __hip_bfloat16* __restrict__ kout,
    __hip_bfloat16* __restrict__ vtout) {
  const int z = blockIdx.z;
  const __hip_bfloat16* __restrict__ W = wb + ((size_t)z << 20);
  const int n0 = blockIdx.x * 128;
  const int m0 = blockIdx.y * 256;
  __shared__ __align__(16) __hip_bfloat16 As[2][256 * 32];  // 2 x 16KB
  __shared__ __align__(16) __hip_bfloat16 Bs[2][128 * 32];  // 2 x 8KB
  const int t = threadIdx.x;
  const int lane = t & 63, wid = t >> 6;
  const int wr = wid >> 1, wc = wid & 1;       // 4M x 2N waves
  const int l15 = lane & 15, lhi = lane >> 4;

  f32x4 acc[4][4] = {};

  // staging: A = 256 rows x 4 chunks(16B) = 1024 slots (2 rounds of 512);
  //          B = 128 rows x 4 chunks = 512 slots (1 round)
  const int srow = t >> 2, sch = (t & 3) * 8;
  const __hip_bfloat16* aS0 = xb + (size_t)(m0 + srow) * 1024 + sch;
  const __hip_bfloat16* aS1 = xb + (size_t)(m0 + 128 + srow) * 1024 + sch;
  const __hip_bfloat16* bS0 = W + (size_t)(n0 + srow) * 1024 + sch;

  // prologue: stage K-tile 0 (wave-linear LDS dests: slot = t, round2 = t+512)
  gload_lds16(aS0, &As[0][wid * 512]);
  gload_lds16(aS1, &As[0][4096 + wid * 512]);
  gload_lds16(bS0, &Bs[0][wid * 512]);
  __syncthreads();

  int cur = 0;
  for (int k0 = 0; k0 < 1024; k0 += 32) {
    if (k0 < 992) {  // issue next-tile staging BEFORE compute
      gload_lds16(aS0 + k0 + 32, &As[cur ^ 1][wid * 512]);
      gload_lds16(aS1 + k0 + 32, &As[cur ^ 1][4096 + wid * 512]);
      gload_lds16(bS0 + k0 + 32, &Bs[cur ^ 1][wid * 512]);
    }
    bf16x8 a[4], b[4];
#pragma unroll
    for (int mf = 0; mf < 4; ++mf)
      a[mf] = *(const bf16x8*)&As[cur][(wr * 64 + mf * 16 + l15) * 32 + lhi * 8];
#pragma unroll
    for (int nf = 0; nf < 4; ++nf)
      b[nf] = *(const bf16x8*)&Bs[cur][(wc * 64 + nf * 16 + l15) * 32 + lhi * 8];
    __builtin_amdgcn_s_setprio(1);
#pragma unroll
    for (int mf = 0; mf < 4; ++mf)
#pragma unroll
      for (int nf = 0; nf < 4; ++nf)
        acc[mf][nf] = MFMA16(a[mf], b[nf], acc[mf][nf]);
    __builtin_amdgcn_s_setprio(0);
    __syncthreads();  // drains prefetch + guards buffer swap
    cur ^= 1;
  }

  const float* __restrict__ bias = (z == 0) ? bq : (z == 1) ? bk : bv;
  // fold 1/sqrt(hd) AND log2(e) into q so attention works in exp2 domain
  const float qscale = (z == 0) ? 0.125f * 1.4426950408889634f : 1.0f;
#pragma unroll
  for (int nf = 0; nf < 4; ++nf) {
    const int col = n0 + wc * 64 + nf * 16 + l15;
    const float bb = bias[col];
    const int h = col >> 6, hd = col & 63;
#pragma unroll
    for (int mf = 0; mf < 4; ++mf) {
      const int mbase = m0 + wr * 64 + mf * 16 + (lhi << 2);
      const int b_ = mbase >> 11, li0 = mbase & 2047;
      if (z == 2) {
        // pack 4 consecutive-li bf16 into one 8B store (avoids 2B scatter)
        u16x4 pk;
#pragma unroll
        for (int r = 0; r < 4; ++r) {
          const __hip_bfloat16 yb = __float2bfloat16(acc[mf][nf][r] + bb);
          pk[r] = *(const unsigned short*)&yb;
        }
        *(u16x4*)&vtout[(((size_t)b_ * 16 + h) * 64 + hd) * 2048 + li0] = pk;
      } else {
#pragma unroll
        for (int r = 0; r < 4; ++r) {
          const float y = (acc[mf][nf][r] + bb) * qscale;
          const __hip_bfloat16 yb = __float2bfloat16(y);
          if (z == 1) kout[(((size_t)b_ * 16 + h) * 2048 + li0 + r) * 64 + hd] = yb;
          else        qout[(((size_t)b_ * 16 + h) * 2048 + li0 + r) * 64 + hd] = yb;
        }
      }
    }
  }
}

// ---------------- flash attention v4: 8 waves, q-tile 256 ----------------
// q,k: [64][2048][64] bf16 (q pre-scaled by 0.125*log2e); vt: [64][64][2048] bf16
// out: [8192][1024] bf16. Block: 8 waves, 32 q/wave, KVBLK=64, dbuf LDS, 2 blocks/CU.
__global__ __launch_bounds__(512, 4) void attn_k(
    const __hip_bfloat16* __restrict__ q, const __hip_bfloat16* __restrict__ k,
    const __hip_bfloat16* __restrict__ vt, __hip_bfloat16* __restrict__ o) {
  // bijective XCD swizzle: 512 blocks = 64 bh x 8 q-tiles; 8 heads per XCD
  const int f = blockIdx.x;
  const int w = (f & 7) * 64 + (f >> 3);
  const int qt = w & 7, bh = w >> 3;
  const int q0 = qt * 256;
  const int t = threadIdx.x, lane = t & 63, wid = t >> 6;
  const int l15 = lane & 15, lhi = lane >> 4, lhi4 = lhi << 2;
  const int qw = q0 + wid * 32;  // this wave's 32 q rows

  __shared__ __align__(16) __hip_bfloat16 Ks[2][64 * 64];   // [kv][hd], XOR-swizzled
  __shared__ __align__(16) __hip_bfloat16 Vs[2][64 * 64];   // [d][kv], XOR-swizzled
  __shared__ __align__(16) __hip_bfloat16 Pl[8][32][72];    // per-wave P, 144B rows

  const __hip_bfloat16* __restrict__ qp = q + ((size_t)bh * 2048 + qw) * 64;
  const __hip_bfloat16* __restrict__ kp = k + (size_t)bh * 2048 * 64;
  const __hip_bfloat16* __restrict__ vp = vt + (size_t)bh * 64 * 2048;

  // staging: 64 rows x 8 chunks(16B) = 512 slots = exactly one 512-thread round
  const int r0 = t >> 3, c0 = t & 7;
  const __hip_bfloat16* kS = kp + r0 * 64 + ((c0 ^ (r0 & 7)) << 3);
  const __hip_bfloat16* vS = vp + (size_t)r0 * 2048 + ((c0 ^ (r0 & 7)) << 3);

  // LDS read byte-offsets (global chunk c read at LDS chunk c ^ (row&7))
  int koff[4][2], voff[4][2];
#pragma unroll
  for (int ct = 0; ct < 4; ++ct)
#pragma unroll
    for (int kst = 0; kst < 2; ++kst) {
      koff[ct][kst] = (ct * 16 + l15) * 128 + ((((kst << 2) | lhi) ^ (l15 & 7)) << 4);
      voff[ct][kst] = koff[ct][kst];  // same geometry for Vs
    }

  // Q fragments (B-operand: lane l15 = q row, k = kst*32 + lhi*8)
  bf16x8 qf_[2][2];
#pragma unroll
  for (int g = 0; g < 2; ++g)
#pragma unroll
    for (int kst = 0; kst < 2; ++kst)
      qf_[g][kst] = *(const bf16x8*)(qp + (size_t)(g * 16 + l15) * 64 + kst * 32 + lhi * 8);

  float m_[2] = {-1e30f, -1e30f}, l_[2] = {0.f, 0.f};
  f32x4 oacc[2][4] = {};

  // prologue: stage tile 0
  gload_lds16(kS, &Ks[0][wid * 512]);
  gload_lds16(vS, &Vs[0][wid * 512]);
  __syncthreads();

  int cur = 0;
  for (int it = 0; it < 32; ++it) {
    if (it < 31) {
      const int kv1 = (it + 1) * 64;
      gload_lds16(kS + kv1 * 64, &Ks[cur ^ 1][wid * 512]);
      gload_lds16(vS + kv1,      &Vs[cur ^ 1][wid * 512]);
    }
    const char* kbase = (const char*)&Ks[cur][0];
    const char* vbase = (const char*)&Vs[cur][0];

    // ---- S^T = K Q^T : C[col=l15 -> q, row=lhi*4+r -> kv] ----
    f32x4 s[2][4] = {};
    __builtin_amdgcn_s_setprio(1);
#pragma unroll
    for (int kst = 0; kst < 2; ++kst)
#pragma unroll
      for (int ct = 0; ct < 4; ++ct) {
        bf16x8 kf = *(const bf16x8*)(kbase + koff[ct][kst]);
        s[0][ct] = MFMA16(kf, qf_[0][kst], s[0][ct]);
        s[1][ct] = MFMA16(kf, qf_[1][kst], s[1][ct]);
      }
    __builtin_amdgcn_s_setprio(0);

    // ---- online softmax, log2 domain, lane-local per q-row ----
#pragma unroll
    for (int g = 0; g < 2; ++g) {
      float mt = fmaxf(fmaxf(s[g][0][0], s[g][0][1]), fmaxf(s[g][0][2], s[g][0][3]));
#pragma unroll
      for (int ct = 1; ct < 4; ++ct)
        mt = fmaxf(mt, fmaxf(fmaxf(s[g][ct][0], s[g][ct][1]), fmaxf(s[g][ct][2], s[g][ct][3])));
      mt = fmaxf(mt, __shfl_xor(mt, 16));
      mt = fmaxf(mt, __shfl_xor(mt, 32));
      // defer-max (T13): skip rescale while tile max stays within 2^11 of running max
      if (!__all(mt <= m_[g] + 11.0f)) {
        const float mn = fmaxf(m_[g], mt);
        const float sc = __builtin_amdgcn_exp2f(m_[g] - mn);
        m_[g] = mn;
        l_[g] *= sc;
#pragma unroll
        for (int r = 0; r < 4; ++r) {
          const float scb = __shfl(sc, lhi4 | r);
#pragma unroll
          for (int dt = 0; dt < 4; ++dt) oacc[g][dt][r] *= scb;
        }
      }
      float rs = 0.f;
#pragma unroll
      for (int ct = 0; ct < 4; ++ct) {
        const float p0 = __builtin_amdgcn_exp2f(s[g][ct][0] - m_[g]);
        const float p1 = __builtin_amdgcn_exp2f(s[g][ct][1] - m_[g]);
        const float p2 = __builtin_amdgcn_exp2f(s[g][ct][2] - m_[g]);
        const float p3 = __builtin_amdgcn_exp2f(s[g][ct][3] - m_[g]);
        rs += (p0 + p1) + (p2 + p3);
        u32x2 pk;
        pk[0] = cvt_pk_bf16(p0, p1);
        pk[1] = cvt_pk_bf16(p2, p3);
        *(u32x2*)&Pl[wid][g * 16 + l15][ct * 16 + lhi4] = pk;  // b64, bank-rotating rows
      }
      rs += __shfl_xor(rs, 16);
      rs += __shfl_xor(rs, 32);
      l_[g] += rs;
    }

    // ---- O += P V : A = P (l15 = q row), B = V^T (l15 = d col) ----
    __builtin_amdgcn_s_setprio(1);
#pragma unroll
    for (int kst = 0; kst < 2; ++kst) {
      bf16x8 pa0 = *(const bf16x8*)&Pl[wid][l15][kst * 32 + lhi * 8];
      bf16x8 pa1 = *(const bf16x8*)&Pl[wid][16 + l15][kst * 32 + lhi * 8];
#pragma unroll
      for (int dt = 0; dt < 4; ++dt) {
        bf16x8 vf = *(const bf16x8*)(vbase + voff[dt][kst]);
        oacc[0][dt] = MFMA16(pa0, vf, oacc[0][dt]);
        oacc[1][dt] = MFMA16(pa1, vf, oacc[1][dt]);
      }
    }
    __builtin_amdgcn_s_setprio(0);
    __syncthreads();  // drains prefetch vmcnt + guards buffer swap
    cur ^= 1;
  }

  // ---- normalize + store (oacc: col=l15 -> d, row=lhi*4+r -> q) ----
  const int b_ = bh >> 4, h = bh & 15;
#pragma unroll
  for (int g = 0; g < 2; ++g)
#pragma unroll
    for (int r = 0; r < 4; ++r) {
      const float lb = __shfl(l_[g], lhi4 | r);
      const float inv = __builtin_amdgcn_rcpf(lb);
      const int qrow = qw + g * 16 + lhi4 + r;
#pragma unroll
      for (int dt = 0; dt < 4; ++dt) {
        const int d = dt * 16 + l15;
        o[((size_t)b_ * 2048 + qrow) * 1024 + h * 64 + d] =
            __float2bfloat16(oacc[g][dt][r] * inv);
      }
    }
}

// ---------------- output projection GEMM (256x128, 8 waves, fp32 out) ----------------
__global__ __launch_bounds__(512, 6) void out_gemm_k(
    const __hip_bfloat16* __restrict__ ab, const __hip_bfloat16* __restrict__ W,
    const float* __restrict__ bo, float* __restrict__ out) {
  const int n0 = blockIdx.x * 128;
  const int m0 = blockIdx.y * 256;
  __shared__ __align__(16) __hip_bfloat16 As[2][256 * 32];
  __shared__ __align__(16) __hip_bfloat16 Bs[2][128 * 32];
  const int t = threadIdx.x;
  const int lane = t & 63, wid = t >> 6;
  const int wr = wid >> 1, wc = wid & 1;
  const int l15 = lane & 15, lhi = lane >> 4;

  f32x4 acc[4][4] = {};
  const int srow = t >> 2, sch = (t & 3) * 8;
  const __hip_bfloat16* aS0 = ab + (size_t)(m0 + srow) * 1024 + sch;
  const __hip_bfloat16* aS1 = ab + (size_t)(m0 + 128 + srow) * 1024 + sch;
  const __hip_bfloat16* bS0 = W + (size_t)(n0 + srow) * 1024 + sch;

  gload_lds16(aS0, &As[0][wid * 512]);
  gload_lds16(aS1, &As[0][4096 + wid * 512]);
  gload_lds16(bS0, &Bs[0][wid * 512]);
  __syncthreads();

  int cur = 0;
  for (int k0 = 0; k0 < 1024; k0 += 32) {
    if (k0 < 992) {
      gload_lds16(aS0 + k0 + 32, &As[cur ^ 1][wid * 512]);
      gload_lds16(aS1 + k0 + 32, &As[cur ^ 1][4096 + wid * 512]);
      gload_lds16(bS0 + k0 + 32, &Bs[cur ^ 1][wid * 512]);
    }
    bf16x8 a[4], b[4];
#pragma unroll
    for (int mf = 0; mf < 4; ++mf)
      a[mf] = *(const bf16x8*)&As[cur][(wr * 64 + mf * 16 + l15) * 32 + lhi * 8];
#pragma unroll
    for (int nf = 0; nf < 4; ++nf)
      b[nf] = *(const bf16x8*)&Bs[cur][(wc * 64 + nf * 16 + l15) * 32 + lhi * 8];
    __builtin_amdgcn_s_setprio(1);
#pragma unroll
    for (int mf = 0; mf < 4; ++mf)
#pragma unroll
      for (int nf = 0; nf < 4; ++nf)
        acc[mf][nf] = MFMA16(a[mf], b[nf], acc[mf][nf]);
    __builtin_amdgcn_s_setprio(0);
    __syncthreads();
    cur ^= 1;
  }
#pragma unroll
  for (int nf = 0; nf < 4; ++nf) {
    const int col = n0 + wc * 64 + nf * 16 + l15;
    const float bb = bo[col];
#pragma unroll
    for (int mf = 0; mf < 4; ++mf)
#pragma unroll
      for (int r = 0; r < 4; ++r) {
        const int m = m0 + wr * 64 + mf * 16 + (lhi << 2) + r;
        out[(size_t)m * 1024 + col] = acc[mf][nf][r] + bb;
      }
  }
}

extern "C" void kernel_launch(void* const* d_in, const int* in_sizes, int n_in,
                              void* d_out, int out_size, void* d_ws, size_t ws_size,
                              hipStream_t stream) {
  const float* x  = (const float*)d_in[0];
  const float* Wq = (const float*)d_in[1];
  const float* bq = (const float*)d_in[2];
  const float* Wk = (const float*)d_in[3];
  const float* bk = (const float*)d_in[4];
  const float* Wv = (const float*)d_in[5];
  const float* bv = (const float*)d_in[6];
  const float* Wo = (const float*)d_in[7];
  const float* bo = (const float*)d_in[8];
  float* out = (float*)d_out;
  char* ws = (char*)d_ws;

  // workspace layout (88 MB total)
  __hip_bfloat16* xb  = (__hip_bfloat16*)(ws);                       // 16 MB [8192][1024]
  __hip_bfloat16* wb  = (__hip_bfloat16*)(ws + (16ull << 20));       // 8 MB  [4][1024][1024] q,k,v,o
  __hip_bfloat16* qb  = (__hip_bfloat16*)(ws + (24ull << 20));       // 16 MB [64][2048][64]
  __hip_bfloat16* kb  = (__hip_bfloat16*)(ws + (40ull << 20));       // 16 MB [64][2048][64]
  __hip_bfloat16* vtb = (__hip_bfloat16*)(ws + (56ull << 20));       // 16 MB [64][64][2048]
  __hip_bfloat16* ab  = (__hip_bfloat16*)(ws + (72ull << 20));       // 16 MB [8192][1024]

  cvt_x_k<<<2048, 256, 0, stream>>>(x, (__hip_bfloat162*)xb, (8192 * 1024) / 2);
  cvt_w_k<<<dim3(256, 1, 4), 256, 0, stream>>>(Wq, Wk, Wv, Wo, (__hip_bfloat162*)wb,
                                               (1024 * 1024) / 2);
  proj_gemm_k<<<dim3(8, 32, 3), 512, 0, stream>>>(xb, wb, bq, bk, bv, qb, kb, vtb);
  attn_k<<<512, 512, 0, stream>>>(qb, kb, vtb, ab);
  out_gemm_k<<<dim3(8, 32), 512, 0, stream>>>(ab, wb + 3ull * 1024 * 1024, bo, out);
}

// Round 11
// 305.673 us; speedup vs baseline: 2.8394x; 2.8394x over previous
//
#include <hip/hip_runtime.h>
#include <hip/hip_bf16.h>
#include <stdint.h>

typedef short bf16x8 __attribute__((ext_vector_type(8)));
typedef float f32x4 __attribute__((ext_vector_type(4)));
typedef unsigned short u16x4 __attribute__((ext_vector_type(4)));
typedef unsigned int u32x2 __attribute__((ext_vector_type(2)));

#define MFMA16(a, b, c) __builtin_amdgcn_mfma_f32_16x16x32_bf16((a), (b), (c), 0, 0, 0)

static __device__ __forceinline__ void gload_lds16(const void* g, void* l) {
  typedef const __attribute__((address_space(1))) void* gp_t;
  typedef __attribute__((address_space(3))) void* lp_t;
  __builtin_amdgcn_global_load_lds((gp_t)g, (lp_t)l, 16, 0, 0);
}

// HW packed f32->bf16 (RNE), 1 VALU op for 2 values
static __device__ __forceinline__ unsigned cvt_pk_bf16(float a, float b) {
  unsigned r;
  asm("v_cvt_pk_bf16_f32 %0, %1, %2" : "=v"(r) : "v"(a), "v"(b));
  return r;
}

// ---------------- conversion kernels ----------------
__global__ void cvt_x_k(const float* __restrict__ in, __hip_bfloat162* __restrict__ out, int n2) {
  int i = blockIdx.x * blockDim.x + threadIdx.x;
  int stride = gridDim.x * blockDim.x;
  const float2* in2 = (const float2*)in;
  for (; i < n2; i += stride) {
    float2 v = in2[i];
    out[i] = __float22bfloat162_rn(v);
  }
}

__global__ void cvt_w_k(const float* __restrict__ w0, const float* __restrict__ w1,
                        const float* __restrict__ w2, const float* __restrict__ w3,
                        __hip_bfloat162* __restrict__ out, int n2) {
  const float* w = (blockIdx.z == 0) ? w0 : (blockIdx.z == 1) ? w1 : (blockIdx.z == 2) ? w2 : w3;
  __hip_bfloat162* o = out + (size_t)blockIdx.z * n2;
  int i = blockIdx.x * blockDim.x + threadIdx.x;
  int stride = gridDim.x * blockDim.x;
  const float2* in2 = (const float2*)w;
  for (; i < n2; i += stride) {
    float2 v = in2[i];
    o[i] = __float22bfloat162_rn(v);
  }
}

// ---------------- fused QKV projection GEMM (R8 known-good: 128x128, 256 thr, 2-phase dbuf) ----------------
// C[m][n] = sum_k xb[m][k] * W[n][k] + bias[n]
// z=0 -> q (scaled by 0.125*log2e, layout [bh][l][hd]); z=1 -> k; z=2 -> v^T ([bh][hd][L])
__global__ __launch_bounds__(256) void proj_gemm_k(
    const __hip_bfloat16* __restrict__ xb, const __hip_bfloat16* __restrict__ wb,
    const float* __restrict__ bq, const float* __restrict__ bk, const float* __restrict__ bv,
    __hip_bfloat16* __restrict__ qout, __hip_bfloat16* __restrict__ kout,
    __hip_bfloat16* __restrict__ vtout) {
  const int z = blockIdx.z;
  const __hip_bfloat16* __restrict__ W = wb + ((size_t)z << 20);
  const int n0 = blockIdx.x * 128;
  const int m0 = blockIdx.y * 128;
  __shared__ __align__(16) __hip_bfloat16 As[2][128 * 32];
  __shared__ __align__(16) __hip_bfloat16 Bs[2][128 * 32];
  const int t = threadIdx.x;
  const int lane = t & 63, wid = t >> 6;
  const int wr = wid >> 1, wc = wid & 1;
  const int l15 = lane & 15, lhi = lane >> 4;

  f32x4 acc[4][4] = {};

  const int srow = t >> 2, sch = (t & 3) * 8;  // staging: 16B chunk per thread
  const __hip_bfloat16* aS0 = xb + (size_t)(m0 + srow) * 1024 + sch;
  const __hip_bfloat16* aS1 = xb + (size_t)(m0 + srow + 64) * 1024 + sch;
  const __hip_bfloat16* bS0 = W + (size_t)(n0 + srow) * 1024 + sch;
  const __hip_bfloat16* bS1 = W + (size_t)(n0 + srow + 64) * 1024 + sch;

  // prologue: stage K-tile 0
  gload_lds16(aS0, &As[0][wid * 512]);
  gload_lds16(aS1, &As[0][2048 + wid * 512]);
  gload_lds16(bS0, &Bs[0][wid * 512]);
  gload_lds16(bS1, &Bs[0][2048 + wid * 512]);
  __syncthreads();

  int cur = 0;
  for (int k0 = 0; k0 < 1024; k0 += 32) {
    if (k0 < 992) {  // issue next-tile staging BEFORE compute (latency hides under MFMAs)
      gload_lds16(aS0 + k0 + 32, &As[cur ^ 1][wid * 512]);
      gload_lds16(aS1 + k0 + 32, &As[cur ^ 1][2048 + wid * 512]);
      gload_lds16(bS0 + k0 + 32, &Bs[cur ^ 1][wid * 512]);
      gload_lds16(bS1 + k0 + 32, &Bs[cur ^ 1][2048 + wid * 512]);
    }
    bf16x8 a[4], b[4];
#pragma unroll
    for (int mf = 0; mf < 4; ++mf)
      a[mf] = *(const bf16x8*)&As[cur][(wr * 64 + mf * 16 + l15) * 32 + lhi * 8];
#pragma unroll
    for (int nf = 0; nf < 4; ++nf)
      b[nf] = *(const bf16x8*)&Bs[cur][(wc * 64 + nf * 16 + l15) * 32 + lhi * 8];
#pragma unroll
    for (int mf = 0; mf < 4; ++mf)
#pragma unroll
      for (int nf = 0; nf < 4; ++nf)
        acc[mf][nf] = MFMA16(a[mf], b[nf], acc[mf][nf]);
    __syncthreads();  // drains prefetch vmcnt + guards buffer swap
    cur ^= 1;
  }

  const float* __restrict__ bias = (z == 0) ? bq : (z == 1) ? bk : bv;
  // fold 1/sqrt(hd) AND log2(e) into q so attention works in exp2 domain
  const float qscale = (z == 0) ? 0.125f * 1.4426950408889634f : 1.0f;
#pragma unroll
  for (int nf = 0; nf < 4; ++nf) {
    const int col = n0 + wc * 64 + nf * 16 + l15;
    const float bb = bias[col];
    const int h = col >> 6, hd = col & 63;
#pragma unroll
    for (int mf = 0; mf < 4; ++mf) {
      const int mbase = m0 + wr * 64 + mf * 16 + lhi * 4;
      const int b_ = mbase >> 11, li0 = mbase & 2047;
      if (z == 2) {
        // pack 4 consecutive-li bf16 into one 8B store (avoids 2B scatter)
        u16x4 pk;
#pragma unroll
        for (int r = 0; r < 4; ++r) {
          const __hip_bfloat16 yb = __float2bfloat16(acc[mf][nf][r] + bb);
          pk[r] = *(const unsigned short*)&yb;
        }
        *(u16x4*)&vtout[(((size_t)b_ * 16 + h) * 64 + hd) * 2048 + li0] = pk;
      } else {
#pragma unroll
        for (int r = 0; r < 4; ++r) {
          const float y = (acc[mf][nf][r] + bb) * qscale;
          const __hip_bfloat16 yb = __float2bfloat16(y);
          if (z == 1) kout[(((size_t)b_ * 16 + h) * 2048 + li0 + r) * 64 + hd] = yb;
          else        qout[(((size_t)b_ * 16 + h) * 2048 + li0 + r) * 64 + hd] = yb;
        }
      }
    }
  }
}

// ---------------- flash attention v4: 8 waves, q-tile 256 ----------------
// q,k: [64][2048][64] bf16 (q pre-scaled by 0.125*log2e); vt: [64][64][2048] bf16
// out: [8192][1024] bf16. Block: 8 waves, 32 q/wave, KVBLK=64, dbuf LDS, 2 blocks/CU.
__global__ __launch_bounds__(512, 4) void attn_k(
    const __hip_bfloat16* __restrict__ q, const __hip_bfloat16* __restrict__ k,
    const __hip_bfloat16* __restrict__ vt, __hip_bfloat16* __restrict__ o) {
  // bijective XCD swizzle: 512 blocks = 64 bh x 8 q-tiles; 8 heads per XCD
  const int f = blockIdx.x;
  const int w = (f & 7) * 64 + (f >> 3);
  const int qt = w & 7, bh = w >> 3;
  const int q0 = qt * 256;
  const int t = threadIdx.x, lane = t & 63, wid = t >> 6;
  const int l15 = lane & 15, lhi = lane >> 4, lhi4 = lhi << 2;
  const int qw = q0 + wid * 32;  // this wave's 32 q rows

  __shared__ __align__(16) __hip_bfloat16 Ks[2][64 * 64];   // [kv][hd], XOR-swizzled
  __shared__ __align__(16) __hip_bfloat16 Vs[2][64 * 64];   // [d][kv], XOR-swizzled
  __shared__ __align__(16) __hip_bfloat16 Pl[8][32][72];    // per-wave P, 144B rows

  const __hip_bfloat16* __restrict__ qp = q + ((size_t)bh * 2048 + qw) * 64;
  const __hip_bfloat16* __restrict__ kp = k + (size_t)bh * 2048 * 64;
  const __hip_bfloat16* __restrict__ vp = vt + (size_t)bh * 64 * 2048;

  // staging: 64 rows x 8 chunks(16B) = 512 slots = exactly one 512-thread round
  const int r0 = t >> 3, c0 = t & 7;
  const __hip_bfloat16* kS = kp + r0 * 64 + ((c0 ^ (r0 & 7)) << 3);
  const __hip_bfloat16* vS = vp + (size_t)r0 * 2048 + ((c0 ^ (r0 & 7)) << 3);

  // LDS read byte-offsets (global chunk c read at LDS chunk c ^ (row&7))
  int koff[4][2], voff[4][2];
#pragma unroll
  for (int ct = 0; ct < 4; ++ct)
#pragma unroll
    for (int kst = 0; kst < 2; ++kst) {
      koff[ct][kst] = (ct * 16 + l15) * 128 + ((((kst << 2) | lhi) ^ (l15 & 7)) << 4);
      voff[ct][kst] = koff[ct][kst];  // same geometry for Vs
    }

  // Q fragments (B-operand: lane l15 = q row, k = kst*32 + lhi*8)
  bf16x8 qf_[2][2];
#pragma unroll
  for (int g = 0; g < 2; ++g)
#pragma unroll
    for (int kst = 0; kst < 2; ++kst)
      qf_[g][kst] = *(const bf16x8*)(qp + (size_t)(g * 16 + l15) * 64 + kst * 32 + lhi * 8);

  float m_[2] = {-1e30f, -1e30f}, l_[2] = {0.f, 0.f};
  f32x4 oacc[2][4] = {};

  // prologue: stage tile 0
  gload_lds16(kS, &Ks[0][wid * 512]);
  gload_lds16(vS, &Vs[0][wid * 512]);
  __syncthreads();

  int cur = 0;
  for (int it = 0; it < 32; ++it) {
    if (it < 31) {
      const int kv1 = (it + 1) * 64;
      gload_lds16(kS + kv1 * 64, &Ks[cur ^ 1][wid * 512]);
      gload_lds16(vS + kv1,      &Vs[cur ^ 1][wid * 512]);
    }
    const char* kbase = (const char*)&Ks[cur][0];
    const char* vbase = (const char*)&Vs[cur][0];

    // ---- S^T = K Q^T : C[col=l15 -> q, row=lhi*4+r -> kv] ----
    f32x4 s[2][4] = {};
    __builtin_amdgcn_s_setprio(1);
#pragma unroll
    for (int kst = 0; kst < 2; ++kst)
#pragma unroll
      for (int ct = 0; ct < 4; ++ct) {
        bf16x8 kf = *(const bf16x8*)(kbase + koff[ct][kst]);
        s[0][ct] = MFMA16(kf, qf_[0][kst], s[0][ct]);
        s[1][ct] = MFMA16(kf, qf_[1][kst], s[1][ct]);
      }
    __builtin_amdgcn_s_setprio(0);

    // ---- online softmax, log2 domain, lane-local per q-row ----
#pragma unroll
    for (int g = 0; g < 2; ++g) {
      float mt = fmaxf(fmaxf(s[g][0][0], s[g][0][1]), fmaxf(s[g][0][2], s[g][0][3]));
#pragma unroll
      for (int ct = 1; ct < 4; ++ct)
        mt = fmaxf(mt, fmaxf(fmaxf(s[g][ct][0], s[g][ct][1]), fmaxf(s[g][ct][2], s[g][ct][3])));
      mt = fmaxf(mt, __shfl_xor(mt, 16));
      mt = fmaxf(mt, __shfl_xor(mt, 32));
      // defer-max (T13): skip rescale while tile max stays within 2^11 of running max
      if (!__all(mt <= m_[g] + 11.0f)) {
        const float mn = fmaxf(m_[g], mt);
        const float sc = __builtin_amdgcn_exp2f(m_[g] - mn);
        m_[g] = mn;
        l_[g] *= sc;
#pragma unroll
        for (int r = 0; r < 4; ++r) {
          const float scb = __shfl(sc, lhi4 | r);
#pragma unroll
          for (int dt = 0; dt < 4; ++dt) oacc[g][dt][r] *= scb;
        }
      }
      float rs = 0.f;
#pragma unroll
      for (int ct = 0; ct < 4; ++ct) {
        const float p0 = __builtin_amdgcn_exp2f(s[g][ct][0] - m_[g]);
        const float p1 = __builtin_amdgcn_exp2f(s[g][ct][1] - m_[g]);
        const float p2 = __builtin_amdgcn_exp2f(s[g][ct][2] - m_[g]);
        const float p3 = __builtin_amdgcn_exp2f(s[g][ct][3] - m_[g]);
        rs += (p0 + p1) + (p2 + p3);
        u32x2 pk;
        pk[0] = cvt_pk_bf16(p0, p1);
        pk[1] = cvt_pk_bf16(p2, p3);
        *(u32x2*)&Pl[wid][g * 16 + l15][ct * 16 + lhi4] = pk;  // b64, bank-rotating rows
      }
      rs += __shfl_xor(rs, 16);
      rs += __shfl_xor(rs, 32);
      l_[g] += rs;
    }

    // ---- O += P V : A = P (l15 = q row), B = V^T (l15 = d col) ----
    __builtin_amdgcn_s_setprio(1);
#pragma unroll
    for (int kst = 0; kst < 2; ++kst) {
      bf16x8 pa0 = *(const bf16x8*)&Pl[wid][l15][kst * 32 + lhi * 8];
      bf16x8 pa1 = *(const bf16x8*)&Pl[wid][16 + l15][kst * 32 + lhi * 8];
#pragma unroll
      for (int dt = 0; dt < 4; ++dt) {
        bf16x8 vf = *(const bf16x8*)(vbase + voff[dt][kst]);
        oacc[0][dt] = MFMA16(pa0, vf, oacc[0][dt]);
        oacc[1][dt] = MFMA16(pa1, vf, oacc[1][dt]);
      }
    }
    __builtin_amdgcn_s_setprio(0);
    __syncthreads();  // drains prefetch vmcnt + guards buffer swap
    cur ^= 1;
  }

  // ---- normalize + store (oacc: col=l15 -> d, row=lhi*4+r -> q) ----
  const int b_ = bh >> 4, h = bh & 15;
#pragma unroll
  for (int g = 0; g < 2; ++g)
#pragma unroll
    for (int r = 0; r < 4; ++r) {
      const float lb = __shfl(l_[g], lhi4 | r);
      const float inv = __builtin_amdgcn_rcpf(lb);
      const int qrow = qw + g * 16 + lhi4 + r;
#pragma unroll
      for (int dt = 0; dt < 4; ++dt) {
        const int d = dt * 16 + l15;
        o[((size_t)b_ * 2048 + qrow) * 1024 + h * 64 + d] =
            __float2bfloat16(oacc[g][dt][r] * inv);
      }
    }
}

// ---------------- output projection GEMM (R8 known-good: 128x128, 256 thr, fp32 out) ----------------
__global__ __launch_bounds__(256) void out_gemm_k(
    const __hip_bfloat16* __restrict__ ab, const __hip_bfloat16* __restrict__ W,
    const float* __restrict__ bo, float* __restrict__ out) {
  const int n0 = blockIdx.x * 128;
  const int m0 = blockIdx.y * 128;
  __shared__ __align__(16) __hip_bfloat16 As[2][128 * 32];
  __shared__ __align__(16) __hip_bfloat16 Bs[2][128 * 32];
  const int t = threadIdx.x;
  const int lane = t & 63, wid = t >> 6;
  const int wr = wid >> 1, wc = wid & 1;
  const int l15 = lane & 15, lhi = lane >> 4;

  f32x4 acc[4][4] = {};
  const int srow = t >> 2, sch = (t & 3) * 8;
  const __hip_bfloat16* aS0 = ab + (size_t)(m0 + srow) * 1024 + sch;
  const __hip_bfloat16* aS1 = ab + (size_t)(m0 + srow + 64) * 1024 + sch;
  const __hip_bfloat16* bS0 = W + (size_t)(n0 + srow) * 1024 + sch;
  const __hip_bfloat16* bS1 = W + (size_t)(n0 + srow + 64) * 1024 + sch;

  gload_lds16(aS0, &As[0][wid * 512]);
  gload_lds16(aS1, &As[0][2048 + wid * 512]);
  gload_lds16(bS0, &Bs[0][wid * 512]);
  gload_lds16(bS1, &Bs[0][2048 + wid * 512]);
  __syncthreads();

  int cur = 0;
  for (int k0 = 0; k0 < 1024; k0 += 32) {
    if (k0 < 992) {
      gload_lds16(aS0 + k0 + 32, &As[cur ^ 1][wid * 512]);
      gload_lds16(aS1 + k0 + 32, &As[cur ^ 1][2048 + wid * 512]);
      gload_lds16(bS0 + k0 + 32, &Bs[cur ^ 1][wid * 512]);
      gload_lds16(bS1 + k0 + 32, &Bs[cur ^ 1][2048 + wid * 512]);
    }
    bf16x8 a[4], b[4];
#pragma unroll
    for (int mf = 0; mf < 4; ++mf)
      a[mf] = *(const bf16x8*)&As[cur][(wr * 64 + mf * 16 + l15) * 32 + lhi * 8];
#pragma unroll
    for (int nf = 0; nf < 4; ++nf)
      b[nf] = *(const bf16x8*)&Bs[cur][(wc * 64 + nf * 16 + l15) * 32 + lhi * 8];
#pragma unroll
    for (int mf = 0; mf < 4; ++mf)
#pragma unroll
      for (int nf = 0; nf < 4; ++nf)
        acc[mf][nf] = MFMA16(a[mf], b[nf], acc[mf][nf]);
    __syncthreads();
    cur ^= 1;
  }
#pragma unroll
  for (int nf = 0; nf < 4; ++nf) {
    const int col = n0 + wc * 64 + nf * 16 + l15;
    const float bb = bo[col];
#pragma unroll
    for (int mf = 0; mf < 4; ++mf)
#pragma unroll
      for (int r = 0; r < 4; ++r) {
        const int m = m0 + wr * 64 + mf * 16 + lhi * 4 + r;
        out[(size_t)m * 1024 + col] = acc[mf][nf][r] + bb;
      }
  }
}

extern "C" void kernel_launch(void* const* d_in, const int* in_sizes, int n_in,
                              void* d_out, int out_size, void* d_ws, size_t ws_size,
                              hipStream_t stream) {
  const float* x  = (const float*)d_in[0];
  const float* Wq = (const float*)d_in[1];
  const float* bq = (const float*)d_in[2];
  const float* Wk = (const float*)d_in[3];
  const float* bk = (const float*)d_in[4];
  const float* Wv = (const float*)d_in[5];
  const float* bv = (const float*)d_in[6];
  const float* Wo = (const float*)d_in[7];
  const float* bo = (const float*)d_in[8];
  float* out = (float*)d_out;
  char* ws = (char*)d_ws;

  // workspace layout (88 MB total)
  __hip_bfloat16* xb  = (__hip_bfloat16*)(ws);                       // 16 MB [8192][1024]
  __hip_bfloat16* wb  = (__hip_bfloat16*)(ws + (16ull << 20));       // 8 MB  [4][1024][1024] q,k,v,o
  __hip_bfloat16* qb  = (__hip_bfloat16*)(ws + (24ull << 20));       // 16 MB [64][2048][64]
  __hip_bfloat16* kb  = (__hip_bfloat16*)(ws + (40ull << 20));       // 16 MB [64][2048][64]
  __hip_bfloat16* vtb = (__hip_bfloat16*)(ws + (56ull << 20));       // 16 MB [64][64][2048]
  __hip_bfloat16* ab  = (__hip_bfloat16*)(ws + (72ull << 20));       // 16 MB [8192][1024]

  cvt_x_k<<<2048, 256, 0, stream>>>(x, (__hip_bfloat162*)xb, (8192 * 1024) / 2);
  cvt_w_k<<<dim3(256, 1, 4), 256, 0, stream>>>(Wq, Wk, Wv, Wo, (__hip_bfloat162*)wb,
                                               (1024 * 1024) / 2);
  proj_gemm_k<<<dim3(8, 64, 3), 256, 0, stream>>>(xb, wb, bq, bk, bv, qb, kb, vtb);
  attn_k<<<512, 512, 0, stream>>>(qb, kb, vtb, ab);
  out_gemm_k<<<dim3(8, 64), 256, 0, stream>>>(ab, wb + 3ull * 1024 * 1024, bo, out);
}